// Round 5
// baseline (764.893 us; speedup 1.0000x reference)
//
#include <hip/hip_runtime.h>
#include <hip/hip_bf16.h>

// RecoveryODENetwork: fused x_model + GRU-ODE scan + output head, single kernel.
// B=2048, T=256, I=64, XH=128, G=Hd=64, O=24.
// Transposed matmuls Dt = W * h^T with MFMA 16x16x32 bf16.
//   A-frag (weights, const): lane holds A[row=l&15][k=8*(l>>4)+e]
//   B-frag (activations):    lane holds B[k=8*(l>>4)+e][col=l&15]   (col = batch)
//   D:                       lane holds D[row=4*(l>>4)+j][col=l&15] (m89-verified)
// R3: role-split waves. 8 waves: 0-3 critical (recurrence), 4-7 helper (x_model,
//     GI, head), window-balanced (R4).
// R5: occupancy via independent blocks. Tile = 4 valid batch cols, grid = 512
//     -> 2 blocks/CU, 4 waves/SIMD from TWO INDEPENDENT recurrences. Their
//     barriers are uncorrelated, so one block's barrier/LDS-latency stalls are
//     filled by the other block's issue. Cols 4-15 are redundant compute
//     (identical per-lane arithmetic; never stored) -> absmax unchanged.
// Recurrent operands (h, r*h, h') in LDS as bf16 hi+lo splits (exactness).
// Lite barriers (lgkmcnt only) keep x-prefetch global loads in flight.

#define T_STEPS 256

typedef short bf16x8 __attribute__((ext_vector_type(8)));
typedef short short4v __attribute__((ext_vector_type(4)));
typedef float f32x4 __attribute__((ext_vector_type(4)));

#define MFMA(a, b, c) __builtin_amdgcn_mfma_f32_16x16x32_bf16((a), (b), (c), 0, 0, 0)

// LDS-only barrier: orders ds ops across the block WITHOUT draining vmcnt.
__device__ __forceinline__ void barrier_lds() {
  asm volatile("s_waitcnt lgkmcnt(0)\n\ts_barrier" ::: "memory");
}

__device__ __forceinline__ short f2bf(float f) {
  __hip_bfloat16 b = __float2bfloat16(f);
  return __builtin_bit_cast(short, b);
}
__device__ __forceinline__ float bf2f(short s) {
  return __builtin_bit_cast(float, ((unsigned)(unsigned short)s) << 16);
}

__device__ __forceinline__ f32x4 sigm4(f32x4 x) {
  f32x4 r;
#pragma unroll
  for (int j = 0; j < 4; ++j) {
    float e = __builtin_amdgcn_exp2f(-1.442695041f * x[j]);
    r[j] = __builtin_amdgcn_rcpf(1.f + e);
  }
  return r;
}
__device__ __forceinline__ f32x4 tanh4(f32x4 x) {
  f32x4 r;
#pragma unroll
  for (int j = 0; j < 4; ++j) {
    float xx = fmaxf(fminf(x[j], 30.f), -30.f);
    float e = __builtin_amdgcn_exp2f(-2.885390082f * xx);  // e^{-2x}
    r[j] = (1.f - e) * __builtin_amdgcn_rcpf(1.f + e);
  }
  return r;
}
__device__ __forceinline__ short4v cvt4(f32x4 v) {
  short4v p;
#pragma unroll
  for (int j = 0; j < 4; ++j) p[j] = f2bf(v[j]);
  return p;
}
// hi = truncate (1 op), lo = RNE(residual). Combined error ~2^-17 rel.
__device__ __forceinline__ void split4(f32x4 v, short4v& hi, short4v& lo) {
#pragma unroll
  for (int j = 0; j < 4; ++j) {
    unsigned u = __builtin_bit_cast(unsigned, v[j]);
    hi[j] = (short)(u >> 16);
    lo[j] = f2bf(v[j] - __builtin_bit_cast(float, u & 0xFFFF0000u));
  }
}
__device__ __forceinline__ bf16x8 wfrag(const float* __restrict__ W, int stride, int row, int c0) {
  const float* p = W + (size_t)row * stride + c0;
  float4 a = *(const float4*)p;
  float4 b = *(const float4*)(p + 4);
  bf16x8 r;
  r[0] = f2bf(a.x); r[1] = f2bf(a.y); r[2] = f2bf(a.z); r[3] = f2bf(a.w);
  r[4] = f2bf(b.x); r[5] = f2bf(b.y); r[6] = f2bf(b.z); r[7] = f2bf(b.w);
  return r;
}

// XOR swizzle (G4): kills 16-way bank conflict of stride-128B/256B column reads
__device__ __forceinline__ int swz64(int row, int off) { return row * 128 + (off ^ ((row & 7) << 4)); }
__device__ __forceinline__ int swzH(int row, int off)  { return row * 256 + (off ^ ((row & 7) << 4)); }

__global__ __launch_bounds__(512, 1) void odegru(
    const float* __restrict__ H,
    const float* __restrict__ W1, const float* __restrict__ b1,
    const float* __restrict__ W2, const float* __restrict__ b2,
    const float* __restrict__ Wor, const float* __restrict__ Woz, const float* __restrict__ Woh,
    const float* __restrict__ wih, const float* __restrict__ whhg,
    const float* __restrict__ bih, const float* __restrict__ bhh,
    const float* __restrict__ Wr, const float* __restrict__ br,
    float* __restrict__ out) {
  const int tid = threadIdx.x;
  const int w = tid >> 6;          // wave 0..7
  const int l = tid & 63;
  const int col = l & 15;          // batch column within tile (0..3 valid)
  const int g = l >> 4;            // lane group
  const int b0 = blockIdx.x << 2;  // 4 valid cols per block
  const bool helper = (w >= 4);
  const int hw = w - 4;            // helper wave index 0..3
  const bool colv = (col < 4);     // valid (stored) column?

  __shared__ __align__(16) char sm[30720];
  char* HIDb = sm;            // [16 cols][256B] bf16 hid (x_model stage1), swizzled
  char* XGb  = sm + 4096;     // [16 cols][128B] bf16 xg, swizzled
  char* Hhi  = sm + 6144;     // h state hi
  char* Hlo  = sm + 8192;     // h state lo
  char* RHhi = sm + 10240;    // r*h hi
  char* RHlo = sm + 12288;    // r*h lo
  char* H2hi = sm + 14336;    // h' hi
  char* H2lo = sm + 16384;    // h' lo
  char* GIb  = sm + 18432;    // [gate3][wave4][lane64] float4 = 12288B

  // zero h state (hi+lo): 4096B, 512 threads x 8B
  ((long long*)Hhi)[tid] = 0;

  // ---- common LDS offsets ----
  const int row4 = 16 * (helper ? hw : w) + 4 * g;  // D-row base of this wave's tile
  const int r16 = 16 * (helper ? hw : w) + col;     // A-frag row base
  const int sR0 = swz64(col, 16 * g);
  const int sR1 = swz64(col, 64 + 16 * g);
  const int sW  = swz64(col, row4 * 2);

  // =======================================================================
  // per-role setup
  // =======================================================================
  bf16x8 aR0, aR1, aZ0, aZ1, aU0, aU1, aHR0, aHR1, aHZ0, aHZ1, aHN0, aHN1;
  f32x4 bhn;
  bf16x8 aW1_00, aW1_01, aW1_10, aW1_11, aW2_0, aW2_1, aW2_2, aW2_3;
  bf16x8 aIR0, aIR1, aIZ0, aIZ1, aIN0, aIN1, aWr0, aWr1;
  f32x4 bsr, bsz, bin_, b1a, b1b, b2w, brw;
  const float* xp = nullptr;
  float4 xa, xb, xc, xd;
  float* outp = nullptr;
  int sHid0, sHid1, sHid2, sHid3, sHidW0, sHidW1, giW;
  const int giR = (w * 64 + l) * 16;  // identity mapping to helper hw==w, same lane

  if (!helper) {
    aR0 = wfrag(Wor, 64, r16, 8 * g);          aR1 = wfrag(Wor, 64, r16, 32 + 8 * g);
    aZ0 = wfrag(Woz, 64, r16, 8 * g);          aZ1 = wfrag(Woz, 64, r16, 32 + 8 * g);
    aU0 = wfrag(Woh, 64, r16, 8 * g);          aU1 = wfrag(Woh, 64, r16, 32 + 8 * g);
    aHR0 = wfrag(whhg, 64, r16, 8 * g);        aHR1 = wfrag(whhg, 64, r16, 32 + 8 * g);
    aHZ0 = wfrag(whhg, 64, 64 + r16, 8 * g);   aHZ1 = wfrag(whhg, 64, 64 + r16, 32 + 8 * g);
    aHN0 = wfrag(whhg, 64, 128 + r16, 8 * g);  aHN1 = wfrag(whhg, 64, 128 + r16, 32 + 8 * g);
#pragma unroll
    for (int j = 0; j < 4; ++j) bhn[j] = bhh[128 + row4 + j];
  } else {
    aW1_00 = wfrag(W1, 64, r16, 8 * g);        aW1_01 = wfrag(W1, 64, r16, 32 + 8 * g);
    aW1_10 = wfrag(W1, 64, 64 + r16, 8 * g);   aW1_11 = wfrag(W1, 64, 64 + r16, 32 + 8 * g);
    aW2_0 = wfrag(W2, 128, r16, 8 * g);        aW2_1 = wfrag(W2, 128, r16, 32 + 8 * g);
    aW2_2 = wfrag(W2, 128, r16, 64 + 8 * g);   aW2_3 = wfrag(W2, 128, r16, 96 + 8 * g);
    aIR0 = wfrag(wih, 64, r16, 8 * g);         aIR1 = wfrag(wih, 64, r16, 32 + 8 * g);
    aIZ0 = wfrag(wih, 64, 64 + r16, 8 * g);    aIZ1 = wfrag(wih, 64, 64 + r16, 32 + 8 * g);
    aIN0 = wfrag(wih, 64, 128 + r16, 8 * g);   aIN1 = wfrag(wih, 64, 128 + r16, 32 + 8 * g);
    const int wr_row = r16 > 23 ? 23 : r16;    // Wr has 24 rows; clamp (unused rows)
    aWr0 = wfrag(Wr, 64, wr_row, 8 * g);       aWr1 = wfrag(Wr, 64, wr_row, 32 + 8 * g);
#pragma unroll
    for (int j = 0; j < 4; ++j) {
      bsr[j] = bih[row4 + j] + bhh[row4 + j];
      bsz[j] = bih[64 + row4 + j] + bhh[64 + row4 + j];
      bin_[j] = bih[128 + row4 + j];
      b1a[j] = b1[row4 + j];
      b1b[j] = b1[64 + row4 + j];
      b2w[j] = b2[row4 + j];
      int o = row4 + j;
      brw[j] = br[o > 23 ? 23 : o];
    }
    sHid0 = swzH(col, 16 * g);
    sHid1 = swzH(col, 64 + 16 * g);
    sHid2 = swzH(col, 128 + 16 * g);
    sHid3 = swzH(col, 192 + 16 * g);
    sHidW0 = swzH(col, row4 * 2);
    sHidW1 = swzH(col, (64 + row4) * 2);
    giW = (hw * 64 + l) * 16;
    // duplicate x reads for cols 4-15 (col&3): L2-absorbed; keeps lane math identical
    xp = H + ((size_t)(b0 + (col & 3)) * T_STEPS) * 64 + 8 * g;
    xa = *(const float4*)(xp);      xb = *(const float4*)(xp + 4);
    xc = *(const float4*)(xp + 32); xd = *(const float4*)(xp + 36);
    outp = out + ((size_t)(b0 + (col & 3)) * T_STEPS) * 24 + row4;
  }

  f32x4 hreg = {0.f, 0.f, 0.f, 0.f};  // critical: h^T[row4+j][col] in fp32

  // =======================================================================
  // prologue: helpers compute hid_0, xg_0 so GI_0 is ready in loop iter 0
  // =======================================================================
  if (helper) {
    bf16x8 xB0, xB1;
    xB0[0] = f2bf(xa.x); xB0[1] = f2bf(xa.y); xB0[2] = f2bf(xa.z); xB0[3] = f2bf(xa.w);
    xB0[4] = f2bf(xb.x); xB0[5] = f2bf(xb.y); xB0[6] = f2bf(xb.z); xB0[7] = f2bf(xb.w);
    xB1[0] = f2bf(xc.x); xB1[1] = f2bf(xc.y); xB1[2] = f2bf(xc.z); xB1[3] = f2bf(xc.w);
    xB1[4] = f2bf(xd.x); xB1[5] = f2bf(xd.y); xB1[6] = f2bf(xd.z); xB1[7] = f2bf(xd.w);
    f32x4 hid0 = b1a;
    hid0 = MFMA(aW1_00, xB0, hid0); hid0 = MFMA(aW1_01, xB1, hid0);
    f32x4 hid1 = b1b;
    hid1 = MFMA(aW1_10, xB0, hid1); hid1 = MFMA(aW1_11, xB1, hid1);
#pragma unroll
    for (int j = 0; j < 4; ++j) { hid0[j] = fmaxf(hid0[j], 0.f); hid1[j] = fmaxf(hid1[j], 0.f); }
    *(short4v*)(HIDb + sHidW0) = cvt4(hid0);
    *(short4v*)(HIDb + sHidW1) = cvt4(hid1);
  }
  barrier_lds();
  if (helper) {
    bf16x8 hdB0 = *(const bf16x8*)(HIDb + sHid0);
    bf16x8 hdB1 = *(const bf16x8*)(HIDb + sHid1);
    bf16x8 hdB2 = *(const bf16x8*)(HIDb + sHid2);
    bf16x8 hdB3 = *(const bf16x8*)(HIDb + sHid3);
    f32x4 xg = b2w;
    xg = MFMA(aW2_0, hdB0, xg); xg = MFMA(aW2_1, hdB1, xg);
    xg = MFMA(aW2_2, hdB2, xg); xg = MFMA(aW2_3, hdB3, xg);
    *(short4v*)(XGb + sW) = cvt4(xg);
    // advance prefetch: regs <- x_1 (consumed in window B of iter 0)
    xp += 64;
    xa = *(const float4*)(xp);      xb = *(const float4*)(xp + 4);
    xc = *(const float4*)(xp + 32); xd = *(const float4*)(xp + 36);
  }
  barrier_lds();

  // =======================================================================
  // main scan
  // =======================================================================
  for (int t = 0; t < T_STEPS; ++t) {
    if (helper) {
      // ============== window A: GI_t (+ head t-1) ==============
      bf16x8 xgB0 = *(const bf16x8*)(XGb + sR0);
      bf16x8 xgB1 = *(const bf16x8*)(XGb + sR1);
      if (hw < 2 && t > 0) {  // output head for t-1 (Hhi/Hlo hold h_{t-1})
        bf16x8 hB0h = *(const bf16x8*)(Hhi + sR0);
        bf16x8 hB1h = *(const bf16x8*)(Hhi + sR1);
        bf16x8 hB0l = *(const bf16x8*)(Hlo + sR0);
        bf16x8 hB1l = *(const bf16x8*)(Hlo + sR1);
        f32x4 a5 = brw, a5l = {0.f, 0.f, 0.f, 0.f};
        a5 = MFMA(aWr0, hB0h, a5);   a5 = MFMA(aWr1, hB1h, a5);
        a5l = MFMA(aWr0, hB0l, a5l); a5l = MFMA(aWr1, hB1l, a5l);
        a5 += a5l;
        if (colv && (hw == 0 || g < 2)) { outp[0] = a5[0]; outp[1] = a5[1]; outp[2] = a5[2]; outp[3] = a5[3]; }
        outp += 24;
      }
      f32x4 gir = bsr;
      gir = MFMA(aIR0, xgB0, gir); gir = MFMA(aIR1, xgB1, gir);
      f32x4 giz = bsz;
      giz = MFMA(aIZ0, xgB0, giz); giz = MFMA(aIZ1, xgB1, giz);
      f32x4 gin = bin_;
      gin = MFMA(aIN0, xgB0, gin); gin = MFMA(aIN1, xgB1, gin);
      *(f32x4*)(GIb + 0 * 4096 + giW) = gir;
      *(f32x4*)(GIb + 1 * 4096 + giW) = giz;
      *(f32x4*)(GIb + 2 * 4096 + giW) = gin;
      barrier_lds();
      // ============== window B: hid_{t+1} ==============
      if (t + 1 < T_STEPS) {
        bf16x8 xB0, xB1;
        xB0[0] = f2bf(xa.x); xB0[1] = f2bf(xa.y); xB0[2] = f2bf(xa.z); xB0[3] = f2bf(xa.w);
        xB0[4] = f2bf(xb.x); xB0[5] = f2bf(xb.y); xB0[6] = f2bf(xb.z); xB0[7] = f2bf(xb.w);
        xB1[0] = f2bf(xc.x); xB1[1] = f2bf(xc.y); xB1[2] = f2bf(xc.z); xB1[3] = f2bf(xc.w);
        xB1[4] = f2bf(xd.x); xB1[5] = f2bf(xd.y); xB1[6] = f2bf(xd.z); xB1[7] = f2bf(xd.w);
        if (t + 2 < T_STEPS) {  // prefetch x_{t+2}; stays in flight across lite barriers
          xp += 64;
          xa = *(const float4*)(xp);      xb = *(const float4*)(xp + 4);
          xc = *(const float4*)(xp + 32); xd = *(const float4*)(xp + 36);
        }
        f32x4 hid0 = b1a;
        hid0 = MFMA(aW1_00, xB0, hid0); hid0 = MFMA(aW1_01, xB1, hid0);
        f32x4 hid1 = b1b;
        hid1 = MFMA(aW1_10, xB0, hid1); hid1 = MFMA(aW1_11, xB1, hid1);
#pragma unroll
        for (int j = 0; j < 4; ++j) { hid0[j] = fmaxf(hid0[j], 0.f); hid1[j] = fmaxf(hid1[j], 0.f); }
        *(short4v*)(HIDb + sHidW0) = cvt4(hid0);
        *(short4v*)(HIDb + sHidW1) = cvt4(hid1);
      }
      barrier_lds();
      // ============== window C: xg_{t+1} ==============
      if (t + 1 < T_STEPS) {
        bf16x8 hdB0 = *(const bf16x8*)(HIDb + sHid0);
        bf16x8 hdB1 = *(const bf16x8*)(HIDb + sHid1);
        bf16x8 hdB2 = *(const bf16x8*)(HIDb + sHid2);
        bf16x8 hdB3 = *(const bf16x8*)(HIDb + sHid3);
        f32x4 xg = b2w;
        xg = MFMA(aW2_0, hdB0, xg); xg = MFMA(aW2_1, hdB1, xg);
        xg = MFMA(aW2_2, hdB2, xg); xg = MFMA(aW2_3, hdB3, xg);
        *(short4v*)(XGb + sW) = cvt4(xg);
      }
      barrier_lds();
    } else {
      // ============== P0 (window A): r,z from h ==============
      bf16x8 hB0h = *(const bf16x8*)(Hhi + sR0);
      bf16x8 hB1h = *(const bf16x8*)(Hhi + sR1);
      bf16x8 hB0l = *(const bf16x8*)(Hlo + sR0);
      bf16x8 hB1l = *(const bf16x8*)(Hlo + sR1);
      f32x4 rph = {0.f, 0.f, 0.f, 0.f}, rpl = {0.f, 0.f, 0.f, 0.f};
      rph = MFMA(aR0, hB0h, rph); rph = MFMA(aR1, hB1h, rph);
      rpl = MFMA(aR0, hB0l, rpl); rpl = MFMA(aR1, hB1l, rpl);
      f32x4 zph = {0.f, 0.f, 0.f, 0.f}, zpl = {0.f, 0.f, 0.f, 0.f};
      zph = MFMA(aZ0, hB0h, zph); zph = MFMA(aZ1, hB1h, zph);
      zpl = MFMA(aZ0, hB0l, zpl); zpl = MFMA(aZ1, hB1l, zpl);
      f32x4 rr = sigm4(rph + rpl);
      {
        short4v phi, plo; split4(rr * hreg, phi, plo);
        *(short4v*)(RHhi + sW) = phi;
        *(short4v*)(RHlo + sW) = plo;
      }
      f32x4 zz = sigm4(zph + zpl);  // after RH write: overlaps barrier wait
      barrier_lds();
      // ============== P1 (window B): u; ODE Euler ==============
      __builtin_amdgcn_s_setprio(1);
      bf16x8 rhB0h = *(const bf16x8*)(RHhi + sR0);
      bf16x8 rhB1h = *(const bf16x8*)(RHhi + sR1);
      bf16x8 rhB0l = *(const bf16x8*)(RHlo + sR0);
      bf16x8 rhB1l = *(const bf16x8*)(RHlo + sR1);
      f32x4 uph = {0.f, 0.f, 0.f, 0.f}, upl = {0.f, 0.f, 0.f, 0.f};
      uph = MFMA(aU0, rhB0h, uph); uph = MFMA(aU1, rhB1h, uph);
      upl = MFMA(aU0, rhB0l, upl); upl = MFMA(aU1, rhB1l, upl);
      f32x4 uu = tanh4(uph + upl);
      f32x4 hp = hreg + (1.f - zz) * (uu - hreg);  // ODE Euler step (DT=1)
      {
        short4v phi, plo; split4(hp, phi, plo);
        *(short4v*)(H2hi + sW) = phi;
        *(short4v*)(H2lo + sW) = plo;
      }
      barrier_lds();
      // ============== P2 (window C): GRU gates; h_new ==============
      bf16x8 h2B0h = *(const bf16x8*)(H2hi + sR0);
      bf16x8 h2B1h = *(const bf16x8*)(H2hi + sR1);
      bf16x8 h2B0l = *(const bf16x8*)(H2lo + sR0);
      bf16x8 h2B1l = *(const bf16x8*)(H2lo + sR1);
      f32x4 gir = *(const f32x4*)(GIb + 0 * 4096 + giR);
      f32x4 giz = *(const f32x4*)(GIb + 1 * 4096 + giR);
      f32x4 gin = *(const f32x4*)(GIb + 2 * 4096 + giR);

      f32x4 hrh = {0.f, 0.f, 0.f, 0.f}, hrl = {0.f, 0.f, 0.f, 0.f};
      hrh = MFMA(aHR0, h2B0h, hrh); hrh = MFMA(aHR1, h2B1h, hrh);
      hrl = MFMA(aHR0, h2B0l, hrl); hrl = MFMA(aHR1, h2B1l, hrl);
      f32x4 hzh = {0.f, 0.f, 0.f, 0.f}, hzl = {0.f, 0.f, 0.f, 0.f};
      hzh = MFMA(aHZ0, h2B0h, hzh); hzh = MFMA(aHZ1, h2B1h, hzh);
      hzl = MFMA(aHZ0, h2B0l, hzl); hzl = MFMA(aHZ1, h2B1l, hzl);
      f32x4 hnh = bhn, hnl = {0.f, 0.f, 0.f, 0.f};
      hnh = MFMA(aHN0, h2B0h, hnh); hnh = MFMA(aHN1, h2B1h, hnh);
      hnl = MFMA(aHN0, h2B0l, hnl); hnl = MFMA(aHN1, h2B1l, hnl);

      f32x4 r2 = sigm4(gir + hrh + hrl);
      f32x4 z2 = sigm4(giz + hzh + hzl);
      f32x4 nn = tanh4(gin + r2 * (hnh + hnl));
      hreg = (1.f - z2) * nn + z2 * hp;  // h_new
      {
        short4v phi, plo; split4(hreg, phi, plo);
        *(short4v*)(Hhi + sW) = phi;
        *(short4v*)(Hlo + sW) = plo;
      }
      __builtin_amdgcn_s_setprio(0);
      barrier_lds();
    }
  }

  // epilogue: output head for t = T-1 (Hhi/Hlo hold h_{T-1})
  if (helper && hw < 2) {
    bf16x8 hB0h = *(const bf16x8*)(Hhi + sR0);
    bf16x8 hB1h = *(const bf16x8*)(Hhi + sR1);
    bf16x8 hB0l = *(const bf16x8*)(Hlo + sR0);
    bf16x8 hB1l = *(const bf16x8*)(Hlo + sR1);
    f32x4 a5 = brw, a5l = {0.f, 0.f, 0.f, 0.f};
    a5 = MFMA(aWr0, hB0h, a5);   a5 = MFMA(aWr1, hB1h, a5);
    a5l = MFMA(aWr0, hB0l, a5l); a5l = MFMA(aWr1, hB1l, a5l);
    a5 += a5l;
    if (colv && (hw == 0 || g < 2)) { outp[0] = a5[0]; outp[1] = a5[1]; outp[2] = a5[2]; outp[3] = a5[3]; }
  }
}

extern "C" void kernel_launch(void* const* d_in, const int* in_sizes, int n_in,
                              void* d_out, int out_size, void* d_ws, size_t ws_size,
                              hipStream_t stream) {
  (void)in_sizes; (void)n_in; (void)d_ws; (void)ws_size; (void)out_size;
  const float* H   = (const float*)d_in[0];
  // d_in[1] = times (unused: delta_t == 1 -> exactly one Euler step per observation)
  const float* W1  = (const float*)d_in[2];
  const float* b1  = (const float*)d_in[3];
  const float* W2  = (const float*)d_in[4];
  const float* b2  = (const float*)d_in[5];
  const float* Whr = (const float*)d_in[6];
  const float* Whz = (const float*)d_in[7];
  const float* Whh = (const float*)d_in[8];
  const float* wih = (const float*)d_in[9];
  const float* whh = (const float*)d_in[10];
  const float* bih = (const float*)d_in[11];
  const float* bhh = (const float*)d_in[12];
  const float* Wr  = (const float*)d_in[13];
  const float* br  = (const float*)d_in[14];
  float* out = (float*)d_out;

  odegru<<<dim3(2048 / 4), dim3(512), 0, stream>>>(
      H, W1, b1, W2, b2, Whr, Whz, Whh, wih, whh, bih, bhh, Wr, br, out);
}